// Round 13
// baseline (187.615 us; speedup 1.0000x reference)
//
#include <hip/hip_runtime.h>
#include <stdint.h>

typedef __attribute__((ext_vector_type(8))) short  short8;   // 8 bf16 = 4 VGPR MFMA frag
typedef __attribute__((ext_vector_type(4))) float  f32x4;    // MFMA accumulator
typedef __attribute__((ext_vector_type(4))) unsigned short us4;
typedef __attribute__((ext_vector_type(4))) unsigned int u32x4;

static __device__ __forceinline__ unsigned short f2bf(float x) {
  unsigned u = __builtin_bit_cast(unsigned, x);
  u += 0x7FFFu + ((u >> 16) & 1u);          // round-to-nearest-even
  return (unsigned short)(u >> 16);
}

static __device__ __forceinline__ unsigned cvt_pk_bf16(float lo, float hi) {
  unsigned r;
  asm("v_cvt_pk_bf16_f32 %0, %1, %2" : "=v"(r) : "v"(lo), "v"(hi));
  return r;
}

// ------------------------------------------------- fp32 -> bf16 (weights only)
__global__ __launch_bounds__(256) void cvtW(const float* __restrict__ Wq,
                                            const float* __restrict__ Wk,
                                            const float* __restrict__ Wv,
                                            const float* __restrict__ Wo,
                                            unsigned short* __restrict__ wbf) {
  const int y = blockIdx.y;
  const float* in = (y == 0) ? Wq : (y == 1) ? Wk : (y == 2) ? Wv : Wo;
  unsigned short* out = wbf + (size_t)y * 1048576;
  int i = blockIdx.x * 256 + threadIdx.x;
  const int stride = gridDim.x * 256;
  for (; i < 262144; i += stride) {
    f32x4 v = *((const f32x4*)in + i);
    us4 o = { f2bf(v[0]), f2bf(v[1]), f2bf(v[2]), f2bf(v[3]) };
    *((us4*)out + i) = o;
  }
}

// ---------------------- pmask -> f32 bias + per-batch 32-bit dirty-tile mask
__global__ __launch_bounds__(1024) void bias_kernel(const int* __restrict__ pm,
                                                    float* __restrict__ bias,
                                                    unsigned* __restrict__ flagmask) {
  __shared__ unsigned m;
  const int b = blockIdx.x, tid = threadIdx.x;
  if (tid == 0) m = 0;
  __syncthreads();
  const int i0 = b * 2048 + tid;
  const int z0 = pm[i0], z1 = pm[i0 + 1024];
  bias[i0]        = z0 ? 0.f : -1.0e9f;
  bias[i0 + 1024] = z1 ? 0.f : -1.0e9f;
  const int wv = tid >> 6;                  // wave index 0..15 = tile index
  unsigned long long b0 = __ballot(z0 == 0);
  unsigned long long b1 = __ballot(z1 == 0);
  if ((tid & 63) == 0) {
    unsigned bits = (b0 ? (1u << wv) : 0u) | (b1 ? (1u << (wv + 16)) : 0u);
    if (bits) atomicOr(&m, bits);
  }
  __syncthreads();
  if (tid == 0) flagmask[b] = m;
}

// ------------------------------------------------------- async global->LDS 16B
static __device__ __forceinline__ void g2l16(const void* g, void* l) {
  __builtin_amdgcn_global_load_lds(
      (const __attribute__((address_space(1))) void*)g,
      (__attribute__((address_space(3))) void*)l, 16, 0, 0);
}

// ------------------------------------------- fused Q/K/V projection NT GEMM
// A read DIRECTLY as fp32 (q_raw/kv_raw), converted in-register (cvt_pk) and
// ds_write'd into the swizzled LDS layout (kills the cvt6 activation pass).
// B (weights bf16) via global_load_lds. COUNTED-vmcnt pipeline: B prefetch
// stays in flight across both raw s_barriers (vmcnt(6) waits only oldest 2);
// A cvt+write pinned after MFMA body via sched_barrier (T14 issue-early/
// write-late). Linear grid 1536, XCD-affine: xcd = l&7.
__global__ __launch_bounds__(256) void gemm_proj(const float* __restrict__ q_raw,
                                                 const float* __restrict__ kv_raw,
                                                 const unsigned short* __restrict__ wbf,
                                                 unsigned short* __restrict__ Qp,
                                                 unsigned short* __restrict__ Kp,
                                                 unsigned short* __restrict__ Vtp,
                                                 float qscale) {
  __shared__ unsigned short Alds[2][4096];
  __shared__ unsigned short Blds[2][4096];
  const int tid  = threadIdx.x;
  const int lane = tid & 63;
  const int w    = tid >> 6;
  const int g    = lane >> 4;
  const int li   = lane & 15;

  const int l = blockIdx.x;
  const int xcd = l & 7, j = l >> 3;
  const int mstep = j & 7, rn = j >> 3;     // rn in [0,24)
  const int region = rn >> 3;               // 0=Q, 1=K, 2=V
  const int n0 = (rn & 7) * 128;
  const int m0 = (xcd * 8 + mstep) * 128;
  const int wm = (w >> 1) * 64;
  const int wn = (w & 1) * 64;

  const float* Araw = (region == 0) ? q_raw : kv_raw;
  const unsigned short* W = wbf + (size_t)region * 1048576;

  int aoff[4], boff[4];
#pragma unroll
  for (int mi = 0; mi < 4; ++mi) {
    int row = wm + mi * 16 + li;
    aoff[mi] = row * 32 + (g ^ ((row >> 1) & 3)) * 8;
  }
#pragma unroll
  for (int ni = 0; ni < 4; ++ni) {
    int col = wn + ni * 16 + li;
    boff[ni] = col * 32 + (g ^ ((col >> 1) & 3)) * 8;
  }

  const int s1 = tid, s2 = 256 + tid;
  const int r1 = s1 >> 2, gc1 = (s1 & 3) ^ ((r1 >> 1) & 3);
  const int r2 = s2 >> 2, gc2 = (s2 & 3) ^ ((r2 >> 1) & 3);
  const float* fA1 = Araw + (size_t)(m0 + r1) * 1024 + gc1 * 8;
  const float* fA2 = Araw + (size_t)(m0 + r2) * 1024 + gc2 * 8;
  const unsigned short* gB1 = W + (size_t)(n0 + r1) * 1024 + gc1 * 8;
  const unsigned short* gB2 = W + (size_t)(n0 + r2) * 1024 + gc2 * 8;

  f32x4 acc[4][4] = {};

  // prologue: stage tile 0 (A regs -> cvt -> LDS; B g2l16 stays outstanding)
  {
    f32x4 a0 = *(const f32x4*)fA1, a1 = *(const f32x4*)(fA1 + 4);
    f32x4 b0 = *(const f32x4*)fA2, b1 = *(const f32x4*)(fA2 + 4);
    fA1 += 32; fA2 += 32;
    g2l16(gB1, &Blds[0][w * 512]); g2l16(gB2, &Blds[0][2048 + w * 512]);
    gB1 += 32; gB2 += 32;
    u32x4 w1 = { cvt_pk_bf16(a0[0], a0[1]), cvt_pk_bf16(a0[2], a0[3]),
                 cvt_pk_bf16(a1[0], a1[1]), cvt_pk_bf16(a1[2], a1[3]) };
    u32x4 w2 = { cvt_pk_bf16(b0[0], b0[1]), cvt_pk_bf16(b0[2], b0[3]),
                 cvt_pk_bf16(b1[0], b1[1]), cvt_pk_bf16(b1[2], b1[3]) };
    *(u32x4*)&Alds[0][s1 * 8] = w1;
    *(u32x4*)&Alds[0][s2 * 8] = w2;
  }
  asm volatile("s_waitcnt lgkmcnt(0)" ::: "memory");

  int cur = 0;
#pragma unroll 1
  for (int kt = 0; kt < 32; ++kt) {
    f32x4 a0, a1, b0, b1;
    const bool pf = (kt < 31);
    if (pf) {
      // issue next tile: A regs (4 vmem) then B g2l16 (2 vmem)
      a0 = *(const f32x4*)fA1; a1 = *(const f32x4*)(fA1 + 4);
      b0 = *(const f32x4*)fA2; b1 = *(const f32x4*)(fA2 + 4);
      fA1 += 32; fA2 += 32;
      g2l16(gB1, &Blds[cur ^ 1][w * 512]); g2l16(gB2, &Blds[cur ^ 1][2048 + w * 512]);
      gB1 += 32; gB2 += 32;
      asm volatile("s_waitcnt vmcnt(6)" ::: "memory");   // oldest 2 = B(kt) landed
    } else {
      asm volatile("s_waitcnt vmcnt(0)" ::: "memory");
    }
    __builtin_amdgcn_s_barrier();

    // body: current tile fragments + MFMA
    short8 af[4], bf[4];
#pragma unroll
    for (int mi = 0; mi < 4; ++mi) af[mi] = *(const short8*)&Alds[cur][aoff[mi]];
#pragma unroll
    for (int ni = 0; ni < 4; ++ni) bf[ni] = *(const short8*)&Blds[cur][boff[ni]];
#pragma unroll
    for (int mi = 0; mi < 4; ++mi)
#pragma unroll
      for (int ni = 0; ni < 4; ++ni)
        acc[mi][ni] = __builtin_amdgcn_mfma_f32_16x16x32_bf16(af[mi], bf[ni], acc[mi][ni], 0, 0, 0);
    __builtin_amdgcn_sched_barrier(0);    // keep cvt+write AFTER the MFMA body

    if (pf) {
      u32x4 w1 = { cvt_pk_bf16(a0[0], a0[1]), cvt_pk_bf16(a0[2], a0[3]),
                   cvt_pk_bf16(a1[0], a1[1]), cvt_pk_bf16(a1[2], a1[3]) };
      u32x4 w2 = { cvt_pk_bf16(b0[0], b0[1]), cvt_pk_bf16(b0[2], b0[3]),
                   cvt_pk_bf16(b1[0], b1[1]), cvt_pk_bf16(b1[2], b1[3]) };
      *(u32x4*)&Alds[cur ^ 1][s1 * 8] = w1;
      *(u32x4*)&Alds[cur ^ 1][s2 * 8] = w2;
    }
    asm volatile("s_waitcnt lgkmcnt(0)" ::: "memory");   // my ds_writes visible
    __builtin_amdgcn_s_barrier();                        // B(kt+1) stays in flight
    cur ^= 1;
  }

  if (region == 2) {
#pragma unroll
    for (int mi = 0; mi < 4; ++mi) {
      int mb = m0 + wm + mi * 16 + g * 4;
      int bb = mb >> 11, s = mb & 2047;
#pragma unroll
      for (int ni = 0; ni < 4; ++ni) {
        int n = n0 + wn + ni * 16 + li;
        us4 pk = { f2bf(acc[mi][ni][0]), f2bf(acc[mi][ni][1]),
                   f2bf(acc[mi][ni][2]), f2bf(acc[mi][ni][3]) };
        *(us4*)&Vtp[(size_t)(bb * 1024 + n) * 2048 + s] = pk;
      }
    }
  } else {
    unsigned short* C = (region == 0) ? Qp : Kp;
    const float sc = (region == 0) ? qscale : 1.0f;
#pragma unroll
    for (int mi = 0; mi < 4; ++mi) {
      int mb = m0 + wm + mi * 16 + g * 4;
#pragma unroll
      for (int ni = 0; ni < 4; ++ni) {
        int n = n0 + wn + ni * 16 + li;
#pragma unroll
        for (int r = 0; r < 4; ++r)
          C[(size_t)(mb + r) * 1024 + n] = f2bf(acc[mi][ni][r] * sc);
      }
    }
  }
}

// ------------------------------------------------------- output projection GEMM
__global__ __launch_bounds__(256) void gemm_out(const unsigned short* __restrict__ A,
                                                const unsigned short* __restrict__ W,
                                                float* __restrict__ C) {
  __shared__ unsigned short Alds[2][4096];
  __shared__ unsigned short Blds[2][4096];
  const int tid  = threadIdx.x;
  const int lane = tid & 63;
  const int w    = tid >> 6;
  const int g    = lane >> 4;
  const int li   = lane & 15;

  const int l = blockIdx.x;
  const int xcd = l & 7, j = l >> 3;
  const int mstep = j & 7, nt = j >> 3;
  const int m0 = (xcd * 8 + mstep) * 128;
  const int n0 = nt * 128;
  const int wm = (w >> 1) * 64;
  const int wn = (w & 1) * 64;

  int aoff[4], boff[4];
#pragma unroll
  for (int mi = 0; mi < 4; ++mi) {
    int row = wm + mi * 16 + li;
    aoff[mi] = row * 32 + (g ^ ((row >> 1) & 3)) * 8;
  }
#pragma unroll
  for (int ni = 0; ni < 4; ++ni) {
    int col = wn + ni * 16 + li;
    boff[ni] = col * 32 + (g ^ ((col >> 1) & 3)) * 8;
  }

  const int s1 = tid, s2 = 256 + tid;
  const int r1 = s1 >> 2, gc1 = (s1 & 3) ^ ((r1 >> 1) & 3);
  const int r2 = s2 >> 2, gc2 = (s2 & 3) ^ ((r2 >> 1) & 3);
  const unsigned short* gA1 = A + (size_t)(m0 + r1) * 1024 + gc1 * 8;
  const unsigned short* gA2 = A + (size_t)(m0 + r2) * 1024 + gc2 * 8;
  const unsigned short* gB1 = W + (size_t)(n0 + r1) * 1024 + gc1 * 8;
  const unsigned short* gB2 = W + (size_t)(n0 + r2) * 1024 + gc2 * 8;

  f32x4 acc[4][4] = {};

  g2l16(gA1, &Alds[0][w * 512]); g2l16(gA2, &Alds[0][2048 + w * 512]);
  g2l16(gB1, &Blds[0][w * 512]); g2l16(gB2, &Blds[0][2048 + w * 512]);
  gA1 += 32; gA2 += 32; gB1 += 32; gB2 += 32;

  int cur = 0;
#pragma unroll 1
  for (int kt = 0; kt < 32; ++kt) {
    if (kt < 31) {
      g2l16(gA1, &Alds[cur ^ 1][w * 512]); g2l16(gA2, &Alds[cur ^ 1][2048 + w * 512]);
      g2l16(gB1, &Blds[cur ^ 1][w * 512]); g2l16(gB2, &Blds[cur ^ 1][2048 + w * 512]);
      gA1 += 32; gA2 += 32; gB1 += 32; gB2 += 32;
      asm volatile("s_waitcnt vmcnt(4)" ::: "memory");
    } else {
      asm volatile("s_waitcnt vmcnt(0)" ::: "memory");
    }
    __builtin_amdgcn_s_barrier();
    short8 af[4], bf[4];
#pragma unroll
    for (int mi = 0; mi < 4; ++mi) af[mi] = *(const short8*)&Alds[cur][aoff[mi]];
#pragma unroll
    for (int ni = 0; ni < 4; ++ni) bf[ni] = *(const short8*)&Blds[cur][boff[ni]];
#pragma unroll
    for (int mi = 0; mi < 4; ++mi)
#pragma unroll
      for (int ni = 0; ni < 4; ++ni)
        acc[mi][ni] = __builtin_amdgcn_mfma_f32_16x16x32_bf16(af[mi], bf[ni], acc[mi][ni], 0, 0, 0);
    __builtin_amdgcn_s_barrier();
    cur ^= 1;
  }

#pragma unroll
  for (int mi = 0; mi < 4; ++mi) {
    int mb = m0 + wm + mi * 16 + g * 4;
#pragma unroll
    for (int ni = 0; ni < 4; ++ni) {
      int n = n0 + wn + ni * 16 + li;
#pragma unroll
      for (int r = 0; r < 4; ++r)
        C[(size_t)(mb + r) * 1024 + n] = acc[mi][ni][r];
    }
  }
}

// ---------------------------------------------------------------- attention v8
// Swapped QK^T (s = mfma(K, Q)) with PERMUTED K-fragment rows so each lane's
// score output already holds exactly the keys its PV A-slots need (in-lane P,
// no LDS/bpermute). Softmax fully in-register. LDS = 32 KB.
__global__ __launch_bounds__(256, 4) void attn_kernel(const unsigned short* __restrict__ Qp,
                                                      const unsigned short* __restrict__ Kp,
                                                      const unsigned short* __restrict__ Vt,
                                                      const float* __restrict__ bias,
                                                      const unsigned* __restrict__ flagmask,
                                                      unsigned short* __restrict__ att) {
  __shared__ unsigned short Klds[2][64 * 64];   // 16 KB
  __shared__ unsigned short Vlds[2][64 * 64];   // 16 KB

  const int tid = threadIdx.x, lane = tid & 63, w = tid >> 6;
  const int g = lane >> 4, li = lane & 15;

  const int rid = blockIdx.x + (blockIdx.y << 4);
  const int xcd = rid & 7, kk = rid >> 3;
  const int bh = (kk & 7) | (xcd << 3);
  const int b = bh >> 4, h = bh & 15;
  const int tA = kk >> 3, tB = 31 - tA;
  const int nA = tA + 1, nB = tB + 1;

  const unsigned smask = flagmask[b];

  const int s1 = tid, s2 = tid + 256;
  const int r1 = s1 >> 3, c1 = (s1 & 7) ^ (r1 & 7);
  const int r2 = s2 >> 3, c2 = (s2 & 7) ^ (r2 & 7);
  const unsigned short* Kb1 = Kp + (size_t)(b * 2048 + r1) * 1024 + h * 64 + c1 * 8;
  const unsigned short* Kb2 = Kp + (size_t)(b * 2048 + r2) * 1024 + h * 64 + c2 * 8;
  const unsigned short* Vb1 = Vt + (size_t)(b * 1024 + h * 64 + r1) * 2048 + c1 * 8;
  const unsigned short* Vb2 = Vt + (size_t)(b * 1024 + h * 64 + r2) * 2048 + c2 * 8;

  int foffK[2][4], foffV[2][4];
#pragma unroll
  for (int ks = 0; ks < 2; ++ks)
#pragma unroll
    for (int ni = 0; ni < 4; ++ni) {
      const int krow = (ni >> 1) * 32 + (li >> 2) * 8 + (ni & 1) * 4 + (li & 3);
      foffK[ks][ni] = krow * 64 + (((ks * 4 + g) ^ (krow & 7)) * 8);
      const int vrow = ni * 16 + li;
      foffV[ks][ni] = vrow * 64 + (((ks * 4 + g) ^ (vrow & 7)) * 8);
    }

  const float* bbase = bias + b * 2048 + g * 8;

  short8 ones;
#pragma unroll
  for (int j2 = 0; j2 < 8; ++j2) ones[j2] = (short)0x3F80;  // bf16 1.0

  int qw = tA * 64 + w * 16;
  short8 qfr[2];
#pragma unroll
  for (int ks = 0; ks < 2; ++ks)
    qfr[ks] = *(const short8*)&Qp[((size_t)(b * 2048 + qw + li)) * 1024 +
                                  h * 64 + ks * 32 + g * 8];

  f32x4 acco[4] = {};
  f32x4 lacc = {};
  float m = -3.0e38f;                        // running max for q-row qw+li
  const f32x4 Z = {0.f, 0.f, 0.f, 0.f};

  auto stage = [&](int kt, int bufn) {
    const size_t ko = (size_t)kt * 65536, vo = (size_t)kt * 64;
    g2l16(Kb1 + ko, &Klds[bufn][w * 512]);
    g2l16(Kb2 + ko, &Klds[bufn][2048 + w * 512]);
    g2l16(Vb1 + vo, &Vlds[bufn][w * 512]);
    g2l16(Vb2 + vo, &Vlds[bufn][2048 + w * 512]);
  };

  auto body = [&](int kt, bool diag, int buf) {
    f32x4 s[4];
    __builtin_amdgcn_s_setprio(1);
#pragma unroll
    for (int ni = 0; ni < 4; ++ni) {
      short8 kf = *(const short8*)&Klds[buf][foffK[0][ni]];
      s[ni] = __builtin_amdgcn_mfma_f32_16x16x32_bf16(kf, qfr[0], Z, 0, 0, 0);
    }
#pragma unroll
    for (int ni = 0; ni < 4; ++ni) {
      short8 kf = *(const short8*)&Klds[buf][foffK[1][ni]];
      s[ni] = __builtin_amdgcn_mfma_f32_16x16x32_bf16(kf, qfr[1], s[ni], 0, 0, 0);
    }
    __builtin_amdgcn_s_setprio(0);
    if ((smask >> kt) & 1u) {
#pragma unroll
      for (int ni = 0; ni < 4; ++ni) {
        f32x4 bv = *(const f32x4*)&bbase[kt * 64 + (ni >> 1) * 32 + (ni & 1) * 4];
#pragma unroll
        for (int r = 0; r < 4; ++r) s[ni][r] += bv[r];
      }
    }
    if (diag) {
      const int q0 = qw + li;
#pragma unroll
      for (int ni = 0; ni < 4; ++ni) {
        const int kb = kt * 64 + (ni >> 1) * 32 + g * 8 + (ni & 1) * 4;
#pragma unroll
        for (int r = 0; r < 4; ++r)
          if (kb + r > q0) s[ni][r] = -1.0e9f;
      }
    }
    f32x4 tv;
#pragma unroll
    for (int r = 0; r < 4; ++r)
      tv[r] = fmaxf(fmaxf(s[0][r], s[1][r]), fmaxf(s[2][r], s[3][r]));
    float tm = fmaxf(fmaxf(tv[0], tv[1]), fmaxf(tv[2], tv[3]));
    tm = fmaxf(tm, __shfl_xor(tm, 16));
    tm = fmaxf(tm, __shfl_xor(tm, 32));
    if (__any(tm > m + 8.0f)) {
      const float mn = fmaxf(m, tm);
      const float al = __builtin_amdgcn_exp2f(m - mn);
      m = mn;
      float alpv[4];
#pragma unroll
      for (int r = 0; r < 4; ++r)
        alpv[r] = __builtin_bit_cast(float,
            __builtin_amdgcn_ds_bpermute((g * 4 + r) * 4, __builtin_bit_cast(int, al)));
#pragma unroll
      for (int r = 0; r < 4; ++r) {
        lacc[r] *= alpv[r];
#pragma unroll
        for (int df = 0; df < 4; ++df) acco[df][r] *= alpv[r];
      }
    }
    unsigned wpk[4][2];
#pragma unroll
    for (int ni = 0; ni < 4; ++ni) {
#pragma unroll
      for (int a2 = 0; a2 < 2; ++a2) {
        float lo = __builtin_amdgcn_exp2f(s[ni][2 * a2]     - m);
        float hi = __builtin_amdgcn_exp2f(s[ni][2 * a2 + 1] - m);
        wpk[ni][a2] = cvt_pk_bf16(lo, hi);
      }
    }
#pragma unroll
    for (int ks = 0; ks < 2; ++ks) {
      u32x4 pw = { wpk[2 * ks][0], wpk[2 * ks][1], wpk[2 * ks + 1][0], wpk[2 * ks + 1][1] };
      const short8 pa = __builtin_bit_cast(short8, pw);
      short8 vf[4];
#pragma unroll
      for (int df = 0; df < 4; ++df) vf[df] = *(const short8*)&Vlds[buf][foffV[ks][df]];
      __builtin_amdgcn_s_setprio(1);
#pragma unroll
      for (int df = 0; df < 4; ++df)
        acco[df] = __builtin_amdgcn_mfma_f32_16x16x32_bf16(pa, vf[df], acco[df], 0, 0, 0);
      lacc = __builtin_amdgcn_mfma_f32_16x16x32_bf16(pa, ones, lacc, 0, 0, 0);
      __builtin_amdgcn_s_setprio(0);
    }
  };

  auto epilogue = [&]() {
    float inv[4];
#pragma unroll
    for (int r = 0; r < 4; ++r) inv[r] = __builtin_amdgcn_rcpf(lacc[r]);
    const int qb0 = qw + g * 4;
#pragma unroll
    for (int df = 0; df < 4; ++df) {
      const int d = h * 64 + df * 16 + li;
#pragma unroll
      for (int r = 0; r < 4; ++r)
        att[(size_t)(b * 2048 + qb0 + r) * 1024 + d] = f2bf(acco[df][r] * inv[r]);
    }
  };

  stage(0, 0);
  int buf = 0;

#pragma unroll 1
  for (int kt = 0; kt < nA; ++kt) {
    stage((kt + 1 < nA) ? kt + 1 : 0, buf ^ 1);
    asm volatile("s_waitcnt vmcnt(4)" ::: "memory");
    __builtin_amdgcn_s_barrier();
    body(kt, kt == nA - 1, buf);
    __builtin_amdgcn_s_barrier();
    buf ^= 1;
  }

  epilogue();
  qw = tB * 64 + w * 16;
#pragma unroll
  for (int ks = 0; ks < 2; ++ks)
    qfr[ks] = *(const short8*)&Qp[((size_t)(b * 2048 + qw + li)) * 1024 +
                                  h * 64 + ks * 32 + g * 8];
#pragma unroll
  for (int df = 0; df < 4; ++df) acco[df] = Z;
  lacc = Z;
  m = -3.0e38f;

#pragma unroll 1
  for (int kt = 0; kt < nB; ++kt) {
    if (kt + 1 < nB) {
      stage(kt + 1, buf ^ 1);
      asm volatile("s_waitcnt vmcnt(4)" ::: "memory");
    } else {
      asm volatile("s_waitcnt vmcnt(0)" ::: "memory");
    }
    __builtin_amdgcn_s_barrier();
    body(kt, kt == nB - 1, buf);
    __builtin_amdgcn_s_barrier();
    buf ^= 1;
  }

  epilogue();
}

// ---------------------------------------------------------------- launch
extern "C" void kernel_launch(void* const* d_in, const int* in_sizes, int n_in,
                              void* d_out, int out_size, void* d_ws, size_t ws_size,
                              hipStream_t stream) {
  const float* q_raw  = (const float*)d_in[0];
  const float* kv_raw = (const float*)d_in[1];
  const int*   pmask  = (const int*)d_in[2];
  const float* Wq = (const float*)d_in[3];
  const float* Wk = (const float*)d_in[4];
  const float* Wv = (const float*)d_in[5];
  const float* Wo = (const float*)d_in[6];
  float* out = (float*)d_out;

  const size_t NEL = 8388608;   // B*S*D
  const size_t WEL = 1048576;   // D*D
  unsigned short* ws   = (unsigned short*)d_ws;
  unsigned short* att  = ws;              // bf16 attention output
  unsigned short* wbf  = att + NEL;       // Wq,Wk,Wv,Wo bf16 back-to-back
  unsigned short* Qp   = wbf + 4 * WEL;
  unsigned short* Kp   = Qp + NEL;
  unsigned short* Vtp  = Kp + NEL;        // (B,H,DH,S) transposed V
  float*          bias = (float*)(Vtp + NEL);
  unsigned*       flagmask = (unsigned*)(bias + 8192);

  const float sc = 0.125f * 1.44269504088896340736f;  // 1/sqrt(DH) * log2(e)

  cvtW<<<dim3(256, 4), 256, 0, stream>>>(Wq, Wk, Wv, Wo, wbf);
  bias_kernel<<<4, 1024, 0, stream>>>(pmask, bias, flagmask);
  gemm_proj<<<1536, 256, 0, stream>>>(q_raw, kv_raw, wbf, Qp, Kp, Vtp, sc);
  attn_kernel<<<dim3(16, 64), 256, 0, stream>>>(Qp, Kp, Vtp, bias, flagmask, att);
  gemm_out<<<512, 256, 0, stream>>>(att, wbf + 3 * WEL, out);
}

// Round 14
// 177.336 us; speedup vs baseline: 1.0580x; 1.0580x over previous
//
#include <hip/hip_runtime.h>
#include <stdint.h>

typedef __attribute__((ext_vector_type(8))) short  short8;   // 8 bf16 = 4 VGPR MFMA frag
typedef __attribute__((ext_vector_type(4))) float  f32x4;    // MFMA accumulator
typedef __attribute__((ext_vector_type(4))) unsigned short us4;
typedef __attribute__((ext_vector_type(4))) unsigned int u32x4;

static __device__ __forceinline__ unsigned short f2bf(float x) {
  unsigned u = __builtin_bit_cast(unsigned, x);
  u += 0x7FFFu + ((u >> 16) & 1u);          // round-to-nearest-even
  return (unsigned short)(u >> 16);
}

static __device__ __forceinline__ unsigned cvt_pk_bf16(float lo, float hi) {
  unsigned r;
  asm("v_cvt_pk_bf16_f32 %0, %1, %2" : "=v"(r) : "v"(lo), "v"(hi));
  return r;
}

// ------------------------------------------------- fp32 -> bf16 (6 regions)
__global__ __launch_bounds__(256) void cvt6(const float* __restrict__ q_raw,
                                            const float* __restrict__ kv_raw,
                                            const float* __restrict__ Wq,
                                            const float* __restrict__ Wk,
                                            const float* __restrict__ Wv,
                                            const float* __restrict__ Wo,
                                            unsigned short* __restrict__ qbf,
                                            unsigned short* __restrict__ kvbf,
                                            unsigned short* __restrict__ wbf) {
  const int y = blockIdx.y;
  const float* in;
  unsigned short* out;
  int n4;
  if (y == 0)      { in = q_raw;  out = qbf;  n4 = 2097152; }
  else if (y == 1) { in = kv_raw; out = kvbf; n4 = 2097152; }
  else {
    in  = (y == 2) ? Wq : (y == 3) ? Wk : (y == 4) ? Wv : Wo;
    out = wbf + (size_t)(y - 2) * 1048576;
    n4 = 262144;
  }
  int i = blockIdx.x * 256 + threadIdx.x;
  const int stride = gridDim.x * 256;
  for (; i < n4; i += stride) {
    f32x4 v = *((const f32x4*)in + i);
    us4 o = { f2bf(v[0]), f2bf(v[1]), f2bf(v[2]), f2bf(v[3]) };
    *((us4*)out + i) = o;
  }
}

// ---------------------- pmask -> f32 bias + per-batch 32-bit dirty-tile mask
__global__ __launch_bounds__(1024) void bias_kernel(const int* __restrict__ pm,
                                                    float* __restrict__ bias,
                                                    unsigned* __restrict__ flagmask) {
  __shared__ unsigned m;
  const int b = blockIdx.x, tid = threadIdx.x;
  if (tid == 0) m = 0;
  __syncthreads();
  const int i0 = b * 2048 + tid;
  const int z0 = pm[i0], z1 = pm[i0 + 1024];
  bias[i0]        = z0 ? 0.f : -1.0e9f;
  bias[i0 + 1024] = z1 ? 0.f : -1.0e9f;
  const int wv = tid >> 6;                  // wave index 0..15 = tile index
  unsigned long long b0 = __ballot(z0 == 0);
  unsigned long long b1 = __ballot(z1 == 0);
  if ((tid & 63) == 0) {
    unsigned bits = (b0 ? (1u << wv) : 0u) | (b1 ? (1u << (wv + 16)) : 0u);
    if (bits) atomicOr(&m, bits);
  }
  __syncthreads();
  if (tid == 0) flagmask[b] = m;
}

// ------------------------------------------------------- async global->LDS 16B
static __device__ __forceinline__ void g2l16(const void* g, void* l) {
  __builtin_amdgcn_global_load_lds(
      (const __attribute__((address_space(1))) void*)g,
      (__attribute__((address_space(3))) void*)l, 16, 0, 0);
}

// ------------------------------------------- fused Q/K/V projection NT GEMM
// Linear grid of 1536. XCD-affine: xcd = l&7 owns m-tiles [8*xcd, 8*xcd+8).
// 2-phase double-buffered staging pipeline (counted vmcnt(4)).
__global__ __launch_bounds__(256) void gemm_proj(const unsigned short* __restrict__ qbf,
                                                 const unsigned short* __restrict__ kvbf,
                                                 const unsigned short* __restrict__ wbf,
                                                 unsigned short* __restrict__ Qp,
                                                 unsigned short* __restrict__ Kp,
                                                 unsigned short* __restrict__ Vtp,
                                                 float qscale) {
  __shared__ unsigned short Alds[2][4096];
  __shared__ unsigned short Blds[2][4096];
  const int tid  = threadIdx.x;
  const int lane = tid & 63;
  const int w    = tid >> 6;
  const int g    = lane >> 4;
  const int li   = lane & 15;

  const int l = blockIdx.x;
  const int xcd = l & 7, j = l >> 3;
  const int mstep = j & 7, rn = j >> 3;     // rn in [0,24)
  const int region = rn >> 3;               // 0=Q, 1=K, 2=V
  const int n0 = (rn & 7) * 128;
  const int m0 = (xcd * 8 + mstep) * 128;
  const int wm = (w >> 1) * 64;
  const int wn = (w & 1) * 64;

  const unsigned short* A = (region == 0) ? qbf : kvbf;
  const unsigned short* W = wbf + (size_t)region * 1048576;

  int aoff[4], boff[4];
#pragma unroll
  for (int mi = 0; mi < 4; ++mi) {
    int row = wm + mi * 16 + li;
    aoff[mi] = row * 32 + (g ^ ((row >> 1) & 3)) * 8;
  }
#pragma unroll
  for (int ni = 0; ni < 4; ++ni) {
    int col = wn + ni * 16 + li;
    boff[ni] = col * 32 + (g ^ ((col >> 1) & 3)) * 8;
  }

  const int s1 = tid, s2 = 256 + tid;
  const int r1 = s1 >> 2, gc1 = (s1 & 3) ^ ((r1 >> 1) & 3);
  const int r2 = s2 >> 2, gc2 = (s2 & 3) ^ ((r2 >> 1) & 3);
  const unsigned short* gA1 = A + (size_t)(m0 + r1) * 1024 + gc1 * 8;
  const unsigned short* gA2 = A + (size_t)(m0 + r2) * 1024 + gc2 * 8;
  const unsigned short* gB1 = W + (size_t)(n0 + r1) * 1024 + gc1 * 8;
  const unsigned short* gB2 = W + (size_t)(n0 + r2) * 1024 + gc2 * 8;

  f32x4 acc[4][4] = {};

  g2l16(gA1, &Alds[0][w * 512]); g2l16(gA2, &Alds[0][2048 + w * 512]);
  g2l16(gB1, &Blds[0][w * 512]); g2l16(gB2, &Blds[0][2048 + w * 512]);
  gA1 += 32; gA2 += 32; gB1 += 32; gB2 += 32;

  int cur = 0;
#pragma unroll 1
  for (int kt = 0; kt < 32; ++kt) {
    if (kt < 31) {
      g2l16(gA1, &Alds[cur ^ 1][w * 512]); g2l16(gA2, &Alds[cur ^ 1][2048 + w * 512]);
      g2l16(gB1, &Blds[cur ^ 1][w * 512]); g2l16(gB2, &Blds[cur ^ 1][2048 + w * 512]);
      gA1 += 32; gA2 += 32; gB1 += 32; gB2 += 32;
      asm volatile("s_waitcnt vmcnt(4)" ::: "memory");
    } else {
      asm volatile("s_waitcnt vmcnt(0)" ::: "memory");
    }
    __builtin_amdgcn_s_barrier();
    short8 af[4], bf[4];
#pragma unroll
    for (int mi = 0; mi < 4; ++mi) af[mi] = *(const short8*)&Alds[cur][aoff[mi]];
#pragma unroll
    for (int ni = 0; ni < 4; ++ni) bf[ni] = *(const short8*)&Blds[cur][boff[ni]];
#pragma unroll
    for (int mi = 0; mi < 4; ++mi)
#pragma unroll
      for (int ni = 0; ni < 4; ++ni)
        acc[mi][ni] = __builtin_amdgcn_mfma_f32_16x16x32_bf16(af[mi], bf[ni], acc[mi][ni], 0, 0, 0);
    __builtin_amdgcn_s_barrier();
    cur ^= 1;
  }

  if (region == 2) {
#pragma unroll
    for (int mi = 0; mi < 4; ++mi) {
      int mb = m0 + wm + mi * 16 + g * 4;
      int bb = mb >> 11, s = mb & 2047;
#pragma unroll
      for (int ni = 0; ni < 4; ++ni) {
        int n = n0 + wn + ni * 16 + li;
        us4 pk = { f2bf(acc[mi][ni][0]), f2bf(acc[mi][ni][1]),
                   f2bf(acc[mi][ni][2]), f2bf(acc[mi][ni][3]) };
        *(us4*)&Vtp[(size_t)(bb * 1024 + n) * 2048 + s] = pk;
      }
    }
  } else {
    unsigned short* C = (region == 0) ? Qp : Kp;
    const float sc = (region == 0) ? qscale : 1.0f;
#pragma unroll
    for (int mi = 0; mi < 4; ++mi) {
      int mb = m0 + wm + mi * 16 + g * 4;
#pragma unroll
      for (int ni = 0; ni < 4; ++ni) {
        int n = n0 + wn + ni * 16 + li;
#pragma unroll
        for (int r = 0; r < 4; ++r)
          C[(size_t)(mb + r) * 1024 + n] = f2bf(acc[mi][ni][r] * sc);
      }
    }
  }
}

// ------------------------------------------------------- output projection GEMM
__global__ __launch_bounds__(256) void gemm_out(const unsigned short* __restrict__ A,
                                                const unsigned short* __restrict__ W,
                                                float* __restrict__ C) {
  __shared__ unsigned short Alds[2][4096];
  __shared__ unsigned short Blds[2][4096];
  const int tid  = threadIdx.x;
  const int lane = tid & 63;
  const int w    = tid >> 6;
  const int g    = lane >> 4;
  const int li   = lane & 15;

  const int l = blockIdx.x;
  const int xcd = l & 7, j = l >> 3;
  const int mstep = j & 7, nt = j >> 3;
  const int m0 = (xcd * 8 + mstep) * 128;
  const int n0 = nt * 128;
  const int wm = (w >> 1) * 64;
  const int wn = (w & 1) * 64;

  int aoff[4], boff[4];
#pragma unroll
  for (int mi = 0; mi < 4; ++mi) {
    int row = wm + mi * 16 + li;
    aoff[mi] = row * 32 + (g ^ ((row >> 1) & 3)) * 8;
  }
#pragma unroll
  for (int ni = 0; ni < 4; ++ni) {
    int col = wn + ni * 16 + li;
    boff[ni] = col * 32 + (g ^ ((col >> 1) & 3)) * 8;
  }

  const int s1 = tid, s2 = 256 + tid;
  const int r1 = s1 >> 2, gc1 = (s1 & 3) ^ ((r1 >> 1) & 3);
  const int r2 = s2 >> 2, gc2 = (s2 & 3) ^ ((r2 >> 1) & 3);
  const unsigned short* gA1 = A + (size_t)(m0 + r1) * 1024 + gc1 * 8;
  const unsigned short* gA2 = A + (size_t)(m0 + r2) * 1024 + gc2 * 8;
  const unsigned short* gB1 = W + (size_t)(n0 + r1) * 1024 + gc1 * 8;
  const unsigned short* gB2 = W + (size_t)(n0 + r2) * 1024 + gc2 * 8;

  f32x4 acc[4][4] = {};

  g2l16(gA1, &Alds[0][w * 512]); g2l16(gA2, &Alds[0][2048 + w * 512]);
  g2l16(gB1, &Blds[0][w * 512]); g2l16(gB2, &Blds[0][2048 + w * 512]);
  gA1 += 32; gA2 += 32; gB1 += 32; gB2 += 32;

  int cur = 0;
#pragma unroll 1
  for (int kt = 0; kt < 32; ++kt) {
    if (kt < 31) {
      g2l16(gA1, &Alds[cur ^ 1][w * 512]); g2l16(gA2, &Alds[cur ^ 1][2048 + w * 512]);
      g2l16(gB1, &Blds[cur ^ 1][w * 512]); g2l16(gB2, &Blds[cur ^ 1][2048 + w * 512]);
      gA1 += 32; gA2 += 32; gB1 += 32; gB2 += 32;
      asm volatile("s_waitcnt vmcnt(4)" ::: "memory");
    } else {
      asm volatile("s_waitcnt vmcnt(0)" ::: "memory");
    }
    __builtin_amdgcn_s_barrier();
    short8 af[4], bf[4];
#pragma unroll
    for (int mi = 0; mi < 4; ++mi) af[mi] = *(const short8*)&Alds[cur][aoff[mi]];
#pragma unroll
    for (int ni = 0; ni < 4; ++ni) bf[ni] = *(const short8*)&Blds[cur][boff[ni]];
#pragma unroll
    for (int mi = 0; mi < 4; ++mi)
#pragma unroll
      for (int ni = 0; ni < 4; ++ni)
        acc[mi][ni] = __builtin_amdgcn_mfma_f32_16x16x32_bf16(af[mi], bf[ni], acc[mi][ni], 0, 0, 0);
    __builtin_amdgcn_s_barrier();
    cur ^= 1;
  }

#pragma unroll
  for (int mi = 0; mi < 4; ++mi) {
    int mb = m0 + wm + mi * 16 + g * 4;
#pragma unroll
    for (int ni = 0; ni < 4; ++ni) {
      int n = n0 + wn + ni * 16 + li;
#pragma unroll
      for (int r = 0; r < 4; ++r)
        C[(size_t)(mb + r) * 1024 + n] = acc[mi][ni][r];
    }
  }
}

// ---------------------------------------------------------------- attention v8
// Swapped QK^T (s = mfma(K, Q)) with PERMUTED K-fragment rows so each lane's
// score output already holds exactly the keys its PV A-slots need (in-lane P,
// no LDS/bpermute). Softmax fully in-register. LDS = 32 KB.
__global__ __launch_bounds__(256, 4) void attn_kernel(const unsigned short* __restrict__ Qp,
                                                      const unsigned short* __restrict__ Kp,
                                                      const unsigned short* __restrict__ Vt,
                                                      const float* __restrict__ bias,
                                                      const unsigned* __restrict__ flagmask,
                                                      unsigned short* __restrict__ att) {
  __shared__ unsigned short Klds[2][64 * 64];   // 16 KB
  __shared__ unsigned short Vlds[2][64 * 64];   // 16 KB

  const int tid = threadIdx.x, lane = tid & 63, w = tid >> 6;
  const int g = lane >> 4, li = lane & 15;

  const int rid = blockIdx.x + (blockIdx.y << 4);
  const int xcd = rid & 7, kk = rid >> 3;
  const int bh = (kk & 7) | (xcd << 3);
  const int b = bh >> 4, h = bh & 15;
  const int tA = kk >> 3, tB = 31 - tA;
  const int nA = tA + 1, nB = tB + 1;

  const unsigned smask = flagmask[b];

  const int s1 = tid, s2 = tid + 256;
  const int r1 = s1 >> 3, c1 = (s1 & 7) ^ (r1 & 7);
  const int r2 = s2 >> 3, c2 = (s2 & 7) ^ (r2 & 7);
  const unsigned short* Kb1 = Kp + (size_t)(b * 2048 + r1) * 1024 + h * 64 + c1 * 8;
  const unsigned short* Kb2 = Kp + (size_t)(b * 2048 + r2) * 1024 + h * 64 + c2 * 8;
  const unsigned short* Vb1 = Vt + (size_t)(b * 1024 + h * 64 + r1) * 2048 + c1 * 8;
  const unsigned short* Vb2 = Vt + (size_t)(b * 1024 + h * 64 + r2) * 2048 + c2 * 8;

  int foffK[2][4], foffV[2][4];
#pragma unroll
  for (int ks = 0; ks < 2; ++ks)
#pragma unroll
    for (int ni = 0; ni < 4; ++ni) {
      const int krow = (ni >> 1) * 32 + (li >> 2) * 8 + (ni & 1) * 4 + (li & 3);
      foffK[ks][ni] = krow * 64 + (((ks * 4 + g) ^ (krow & 7)) * 8);
      const int vrow = ni * 16 + li;
      foffV[ks][ni] = vrow * 64 + (((ks * 4 + g) ^ (vrow & 7)) * 8);
    }

  const float* bbase = bias + b * 2048 + g * 8;

  short8 ones;
#pragma unroll
  for (int j2 = 0; j2 < 8; ++j2) ones[j2] = (short)0x3F80;  // bf16 1.0

  int qw = tA * 64 + w * 16;
  short8 qfr[2];
#pragma unroll
  for (int ks = 0; ks < 2; ++ks)
    qfr[ks] = *(const short8*)&Qp[((size_t)(b * 2048 + qw + li)) * 1024 +
                                  h * 64 + ks * 32 + g * 8];

  f32x4 acco[4] = {};
  f32x4 lacc = {};
  float m = -3.0e38f;                        // running max for q-row qw+li
  const f32x4 Z = {0.f, 0.f, 0.f, 0.f};

  auto stage = [&](int kt, int bufn) {
    const size_t ko = (size_t)kt * 65536, vo = (size_t)kt * 64;
    g2l16(Kb1 + ko, &Klds[bufn][w * 512]);
    g2l16(Kb2 + ko, &Klds[bufn][2048 + w * 512]);
    g2l16(Vb1 + vo, &Vlds[bufn][w * 512]);
    g2l16(Vb2 + vo, &Vlds[bufn][2048 + w * 512]);
  };

  auto body = [&](int kt, bool diag, int buf) {
    f32x4 s[4];
    __builtin_amdgcn_s_setprio(1);
#pragma unroll
    for (int ni = 0; ni < 4; ++ni) {
      short8 kf = *(const short8*)&Klds[buf][foffK[0][ni]];
      s[ni] = __builtin_amdgcn_mfma_f32_16x16x32_bf16(kf, qfr[0], Z, 0, 0, 0);
    }
#pragma unroll
    for (int ni = 0; ni < 4; ++ni) {
      short8 kf = *(const short8*)&Klds[buf][foffK[1][ni]];
      s[ni] = __builtin_amdgcn_mfma_f32_16x16x32_bf16(kf, qfr[1], s[ni], 0, 0, 0);
    }
    __builtin_amdgcn_s_setprio(0);
    if ((smask >> kt) & 1u) {
#pragma unroll
      for (int ni = 0; ni < 4; ++ni) {
        f32x4 bv = *(const f32x4*)&bbase[kt * 64 + (ni >> 1) * 32 + (ni & 1) * 4];
#pragma unroll
        for (int r = 0; r < 4; ++r) s[ni][r] += bv[r];
      }
    }
    if (diag) {
      const int q0 = qw + li;
#pragma unroll
      for (int ni = 0; ni < 4; ++ni) {
        const int kb = kt * 64 + (ni >> 1) * 32 + g * 8 + (ni & 1) * 4;
#pragma unroll
        for (int r = 0; r < 4; ++r)
          if (kb + r > q0) s[ni][r] = -1.0e9f;
      }
    }
    f32x4 tv;
#pragma unroll
    for (int r = 0; r < 4; ++r)
      tv[r] = fmaxf(fmaxf(s[0][r], s[1][r]), fmaxf(s[2][r], s[3][r]));
    float tm = fmaxf(fmaxf(tv[0], tv[1]), fmaxf(tv[2], tv[3]));
    tm = fmaxf(tm, __shfl_xor(tm, 16));
    tm = fmaxf(tm, __shfl_xor(tm, 32));
    if (__any(tm > m + 8.0f)) {
      const float mn = fmaxf(m, tm);
      const float al = __builtin_amdgcn_exp2f(m - mn);
      m = mn;
      float alpv[4];
#pragma unroll
      for (int r = 0; r < 4; ++r)
        alpv[r] = __builtin_bit_cast(float,
            __builtin_amdgcn_ds_bpermute((g * 4 + r) * 4, __builtin_bit_cast(int, al)));
#pragma unroll
      for (int r = 0; r < 4; ++r) {
        lacc[r] *= alpv[r];
#pragma unroll
        for (int df = 0; df < 4; ++df) acco[df][r] *= alpv[r];
      }
    }
    unsigned wpk[4][2];
#pragma unroll
    for (int ni = 0; ni < 4; ++ni) {
#pragma unroll
      for (int a2 = 0; a2 < 2; ++a2) {
        float lo = __builtin_amdgcn_exp2f(s[ni][2 * a2]     - m);
        float hi = __builtin_amdgcn_exp2f(s[ni][2 * a2 + 1] - m);
        wpk[ni][a2] = cvt_pk_bf16(lo, hi);
      }
    }
#pragma unroll
    for (int ks = 0; ks < 2; ++ks) {
      u32x4 pw = { wpk[2 * ks][0], wpk[2 * ks][1], wpk[2 * ks + 1][0], wpk[2 * ks + 1][1] };
      const short8 pa = __builtin_bit_cast(short8, pw);
      short8 vf[4];
#pragma unroll
      for (int df = 0; df < 4; ++df) vf[df] = *(const short8*)&Vlds[buf][foffV[ks][df]];
      __builtin_amdgcn_s_setprio(1);
#pragma unroll
      for (int df = 0; df < 4; ++df)
        acco[df] = __builtin_amdgcn_mfma_f32_16x16x32_bf16(pa, vf[df], acco[df], 0, 0, 0);
      lacc = __builtin_amdgcn_mfma_f32_16x16x32_bf16(pa, ones, lacc, 0, 0, 0);
      __builtin_amdgcn_s_setprio(0);
    }
  };

  auto epilogue = [&]() {
    float inv[4];
#pragma unroll
    for (int r = 0; r < 4; ++r) inv[r] = __builtin_amdgcn_rcpf(lacc[r]);
    const int qb0 = qw + g * 4;
#pragma unroll
    for (int df = 0; df < 4; ++df) {
      const int d = h * 64 + df * 16 + li;
#pragma unroll
      for (int r = 0; r < 4; ++r)
        att[(size_t)(b * 2048 + qb0 + r) * 1024 + d] = f2bf(acco[df][r] * inv[r]);
    }
  };

  stage(0, 0);
  int buf = 0;

#pragma unroll 1
  for (int kt = 0; kt < nA; ++kt) {
    stage((kt + 1 < nA) ? kt + 1 : 0, buf ^ 1);
    asm volatile("s_waitcnt vmcnt(4)" ::: "memory");
    __builtin_amdgcn_s_barrier();
    body(kt, kt == nA - 1, buf);
    __builtin_amdgcn_s_barrier();
    buf ^= 1;
  }

  epilogue();
  qw = tB * 64 + w * 16;
#pragma unroll
  for (int ks = 0; ks < 2; ++ks)
    qfr[ks] = *(const short8*)&Qp[((size_t)(b * 2048 + qw + li)) * 1024 +
                                  h * 64 + ks * 32 + g * 8];
#pragma unroll
  for (int df = 0; df < 4; ++df) acco[df] = Z;
  lacc = Z;
  m = -3.0e38f;

#pragma unroll 1
  for (int kt = 0; kt < nB; ++kt) {
    if (kt + 1 < nB) {
      stage(kt + 1, buf ^ 1);
      asm volatile("s_waitcnt vmcnt(4)" ::: "memory");
    } else {
      asm volatile("s_waitcnt vmcnt(0)" ::: "memory");
    }
    __builtin_amdgcn_s_barrier();
    body(kt, kt == nB - 1, buf);
    __builtin_amdgcn_s_barrier();
    buf ^= 1;
  }

  epilogue();
}

// ---------------------------------------------------------------- launch
extern "C" void kernel_launch(void* const* d_in, const int* in_sizes, int n_in,
                              void* d_out, int out_size, void* d_ws, size_t ws_size,
                              hipStream_t stream) {
  const float* q_raw  = (const float*)d_in[0];
  const float* kv_raw = (const float*)d_in[1];
  const int*   pmask  = (const int*)d_in[2];
  const float* Wq = (const float*)d_in[3];
  const float* Wk = (const float*)d_in[4];
  const float* Wv = (const float*)d_in[5];
  const float* Wo = (const float*)d_in[6];
  float* out = (float*)d_out;

  const size_t NEL = 8388608;   // B*S*D
  const size_t WEL = 1048576;   // D*D
  unsigned short* ws   = (unsigned short*)d_ws;
  unsigned short* qbf  = ws;              // reused as att after projections
  unsigned short* kvbf = qbf + NEL;
  unsigned short* wbf  = kvbf + NEL;      // Wq,Wk,Wv,Wo bf16 back-to-back
  unsigned short* Qp   = wbf + 4 * WEL;
  unsigned short* Kp   = Qp + NEL;
  unsigned short* Vtp  = Kp + NEL;        // (B,H,DH,S) transposed V
  float*          bias = (float*)(Vtp + NEL);
  unsigned*       flagmask = (unsigned*)(bias + 8192);
  unsigned short* att  = qbf;             // alias (qbf dead after projections)

  const float sc = 0.125f * 1.44269504088896340736f;  // 1/sqrt(DH) * log2(e)

  cvt6<<<dim3(512, 6), 256, 0, stream>>>(q_raw, kv_raw, Wq, Wk, Wv, Wo, qbf, kvbf, wbf);
  bias_kernel<<<4, 1024, 0, stream>>>(pmask, bias, flagmask);
  gemm_proj<<<1536, 256, 0, stream>>>(qbf, kvbf, wbf, Qp, Kp, Vtp, sc);
  attn_kernel<<<dim3(16, 64), 256, 0, stream>>>(Qp, Kp, Vtp, bias, flagmask, att);
  gemm_out<<<512, 256, 0, stream>>>(att, wbf + 3 * WEL, out);
}

// Round 15
// 170.311 us; speedup vs baseline: 1.1016x; 1.0412x over previous
//
#include <hip/hip_runtime.h>
#include <stdint.h>

typedef __attribute__((ext_vector_type(8))) short  short8;   // 8 bf16 = 4 VGPR MFMA frag
typedef __attribute__((ext_vector_type(4))) float  f32x4;    // MFMA accumulator
typedef __attribute__((ext_vector_type(4))) unsigned short us4;
typedef __attribute__((ext_vector_type(4))) unsigned int u32x4;

static __device__ __forceinline__ unsigned short f2bf(float x) {
  unsigned u = __builtin_bit_cast(unsigned, x);
  u += 0x7FFFu + ((u >> 16) & 1u);          // round-to-nearest-even
  return (unsigned short)(u >> 16);
}

static __device__ __forceinline__ unsigned cvt_pk_bf16(float lo, float hi) {
  unsigned r;
  asm("v_cvt_pk_bf16_f32 %0, %1, %2" : "=v"(r) : "v"(lo), "v"(hi));
  return r;
}

// ------------------------------------------------- fp32 -> bf16 (6 regions)
__global__ __launch_bounds__(256) void cvt6(const float* __restrict__ q_raw,
                                            const float* __restrict__ kv_raw,
                                            const float* __restrict__ Wq,
                                            const float* __restrict__ Wk,
                                            const float* __restrict__ Wv,
                                            const float* __restrict__ Wo,
                                            unsigned short* __restrict__ qbf,
                                            unsigned short* __restrict__ kvbf,
                                            unsigned short* __restrict__ wbf) {
  const int y = blockIdx.y;
  const float* in;
  unsigned short* out;
  int n4;
  if (y == 0)      { in = q_raw;  out = qbf;  n4 = 2097152; }
  else if (y == 1) { in = kv_raw; out = kvbf; n4 = 2097152; }
  else {
    in  = (y == 2) ? Wq : (y == 3) ? Wk : (y == 4) ? Wv : Wo;
    out = wbf + (size_t)(y - 2) * 1048576;
    n4 = 262144;
  }
  int i = blockIdx.x * 256 + threadIdx.x;
  const int stride = gridDim.x * 256;
  for (; i < n4; i += stride) {
    f32x4 v = *((const f32x4*)in + i);
    us4 o = { f2bf(v[0]), f2bf(v[1]), f2bf(v[2]), f2bf(v[3]) };
    *((us4*)out + i) = o;
  }
}

// ---------------------- pmask -> f32 bias + per-batch 32-bit dirty-tile mask
__global__ __launch_bounds__(1024) void bias_kernel(const int* __restrict__ pm,
                                                    float* __restrict__ bias,
                                                    unsigned* __restrict__ flagmask) {
  __shared__ unsigned m;
  const int b = blockIdx.x, tid = threadIdx.x;
  if (tid == 0) m = 0;
  __syncthreads();
  const int i0 = b * 2048 + tid;
  const int z0 = pm[i0], z1 = pm[i0 + 1024];
  bias[i0]        = z0 ? 0.f : -1.0e9f;
  bias[i0 + 1024] = z1 ? 0.f : -1.0e9f;
  const int wv = tid >> 6;                  // wave index 0..15 = tile index
  unsigned long long b0 = __ballot(z0 == 0);
  unsigned long long b1 = __ballot(z1 == 0);
  if ((tid & 63) == 0) {
    unsigned bits = (b0 ? (1u << wv) : 0u) | (b1 ? (1u << (wv + 16)) : 0u);
    if (bits) atomicOr(&m, bits);
  }
  __syncthreads();
  if (tid == 0) flagmask[b] = m;
}

// ------------------------------------------------------- async global->LDS 16B
static __device__ __forceinline__ void g2l16(const void* g, void* l) {
  __builtin_amdgcn_global_load_lds(
      (const __attribute__((address_space(1))) void*)g,
      (__attribute__((address_space(3))) void*)l, 16, 0, 0);
}

// ------------------------------------------- fused Q/K/V projection NT GEMM
// 128m x 256n tiles, 512 threads (8 waves, 2Mx4N; wave = 64x64, same per-wave
// resources as the 128^2 version). One A-panel shared across the n-pair:
// A global traffic halves, staging ops -25%. LDS 48 KB (2 blocks/CU by the
// 16-wave VGPR cap). Grid 768, XCD-affine: xcd = l&7 owns m-tiles
// [8*xcd, 8*xcd+8) for all (region, npair). Counted vmcnt(3) pipeline.
__global__ __launch_bounds__(512) void gemm_proj(const unsigned short* __restrict__ qbf,
                                                 const unsigned short* __restrict__ kvbf,
                                                 const unsigned short* __restrict__ wbf,
                                                 unsigned short* __restrict__ Qp,
                                                 unsigned short* __restrict__ Kp,
                                                 unsigned short* __restrict__ Vtp,
                                                 float qscale) {
  __shared__ unsigned short Alds[2][4096];   //  8 KB per buf (128x32)
  __shared__ unsigned short Blds[2][8192];   // 16 KB per buf (256x32)
  const int tid  = threadIdx.x;
  const int lane = tid & 63;
  const int w    = tid >> 6;                 // 0..7
  const int g    = lane >> 4;
  const int li   = lane & 15;

  const int l = blockIdx.x;
  const int xcd = l & 7, j = l >> 3;         // j in [0,96)
  const int mstep = j & 7, rn = j >> 3;      // rn in [0,12)
  const int region = rn >> 2;                // 0=Q, 1=K, 2=V
  const int n0 = (rn & 3) * 256;
  const int m0 = (xcd * 8 + mstep) * 128;
  const int wm = (w >> 2) * 64;              // 0 or 64
  const int wn = (w & 3) * 64;               // 0,64,128,192

  const unsigned short* A = (region == 0) ? qbf : kvbf;
  const unsigned short* W = wbf + (size_t)region * 1048576;

  int aoff[4], boff[4];
#pragma unroll
  for (int mi = 0; mi < 4; ++mi) {
    int row = wm + mi * 16 + li;
    aoff[mi] = row * 32 + (g ^ ((row >> 1) & 3)) * 8;
  }
#pragma unroll
  for (int ni = 0; ni < 4; ++ni) {
    int col = wn + ni * 16 + li;
    boff[ni] = col * 32 + (g ^ ((col >> 1) & 3)) * 8;
  }

  // staging: A = 512 slots (1/thread), B = 1024 slots (2/thread)
  const int rA  = tid >> 2,          cA  = (tid & 3) ^ ((rA >> 1) & 3);
  const int sB2 = tid + 512;
  const int rB1 = tid >> 2,          cB1 = (tid & 3) ^ ((rB1 >> 1) & 3);
  const int rB2 = sB2 >> 2,          cB2 = (sB2 & 3) ^ ((rB2 >> 1) & 3);
  const unsigned short* gA  = A + (size_t)(m0 + rA)  * 1024 + cA  * 8;
  const unsigned short* gB1 = W + (size_t)(n0 + rB1) * 1024 + cB1 * 8;
  const unsigned short* gB2 = W + (size_t)(n0 + rB2) * 1024 + cB2 * 8;

  f32x4 acc[4][4] = {};

  g2l16(gA,  &Alds[0][w * 512]);
  g2l16(gB1, &Blds[0][w * 512]);
  g2l16(gB2, &Blds[0][4096 + w * 512]);
  gA += 32; gB1 += 32; gB2 += 32;

  int cur = 0;
#pragma unroll 1
  for (int kt = 0; kt < 32; ++kt) {
    if (kt < 31) {
      g2l16(gA,  &Alds[cur ^ 1][w * 512]);
      g2l16(gB1, &Blds[cur ^ 1][w * 512]);
      g2l16(gB2, &Blds[cur ^ 1][4096 + w * 512]);
      gA += 32; gB1 += 32; gB2 += 32;
      asm volatile("s_waitcnt vmcnt(3)" ::: "memory");  // current tile's 3 landed
    } else {
      asm volatile("s_waitcnt vmcnt(0)" ::: "memory");
    }
    __builtin_amdgcn_s_barrier();
    short8 af[4], bf[4];
#pragma unroll
    for (int mi = 0; mi < 4; ++mi) af[mi] = *(const short8*)&Alds[cur][aoff[mi]];
#pragma unroll
    for (int ni = 0; ni < 4; ++ni) bf[ni] = *(const short8*)&Blds[cur][boff[ni]];
#pragma unroll
    for (int mi = 0; mi < 4; ++mi)
#pragma unroll
      for (int ni = 0; ni < 4; ++ni)
        acc[mi][ni] = __builtin_amdgcn_mfma_f32_16x16x32_bf16(af[mi], bf[ni], acc[mi][ni], 0, 0, 0);
    __builtin_amdgcn_s_barrier();
    cur ^= 1;
  }

  if (region == 2) {
#pragma unroll
    for (int mi = 0; mi < 4; ++mi) {
      int mb = m0 + wm + mi * 16 + g * 4;
      int bb = mb >> 11, s = mb & 2047;
#pragma unroll
      for (int ni = 0; ni < 4; ++ni) {
        int n = n0 + wn + ni * 16 + li;
        us4 pk = { f2bf(acc[mi][ni][0]), f2bf(acc[mi][ni][1]),
                   f2bf(acc[mi][ni][2]), f2bf(acc[mi][ni][3]) };
        *(us4*)&Vtp[(size_t)(bb * 1024 + n) * 2048 + s] = pk;
      }
    }
  } else {
    unsigned short* C = (region == 0) ? Qp : Kp;
    const float sc = (region == 0) ? qscale : 1.0f;
#pragma unroll
    for (int mi = 0; mi < 4; ++mi) {
      int mb = m0 + wm + mi * 16 + g * 4;
#pragma unroll
      for (int ni = 0; ni < 4; ++ni) {
        int n = n0 + wn + ni * 16 + li;
#pragma unroll
        for (int r = 0; r < 4; ++r)
          C[(size_t)(mb + r) * 1024 + n] = f2bf(acc[mi][ni][r] * sc);
      }
    }
  }
}

// ------------------------------------------------------- output projection GEMM
__global__ __launch_bounds__(256) void gemm_out(const unsigned short* __restrict__ A,
                                                const unsigned short* __restrict__ W,
                                                float* __restrict__ C) {
  __shared__ unsigned short Alds[2][4096];
  __shared__ unsigned short Blds[2][4096];
  const int tid  = threadIdx.x;
  const int lane = tid & 63;
  const int w    = tid >> 6;
  const int g    = lane >> 4;
  const int li   = lane & 15;

  const int l = blockIdx.x;
  const int xcd = l & 7, j = l >> 3;
  const int mstep = j & 7, nt = j >> 3;
  const int m0 = (xcd * 8 + mstep) * 128;
  const int n0 = nt * 128;
  const int wm = (w >> 1) * 64;
  const int wn = (w & 1) * 64;

  int aoff[4], boff[4];
#pragma unroll
  for (int mi = 0; mi < 4; ++mi) {
    int row = wm + mi * 16 + li;
    aoff[mi] = row * 32 + (g ^ ((row >> 1) & 3)) * 8;
  }
#pragma unroll
  for (int ni = 0; ni < 4; ++ni) {
    int col = wn + ni * 16 + li;
    boff[ni] = col * 32 + (g ^ ((col >> 1) & 3)) * 8;
  }

  const int s1 = tid, s2 = 256 + tid;
  const int r1 = s1 >> 2, gc1 = (s1 & 3) ^ ((r1 >> 1) & 3);
  const int r2 = s2 >> 2, gc2 = (s2 & 3) ^ ((r2 >> 1) & 3);
  const unsigned short* gA1 = A + (size_t)(m0 + r1) * 1024 + gc1 * 8;
  const unsigned short* gA2 = A + (size_t)(m0 + r2) * 1024 + gc2 * 8;
  const unsigned short* gB1 = W + (size_t)(n0 + r1) * 1024 + gc1 * 8;
  const unsigned short* gB2 = W + (size_t)(n0 + r2) * 1024 + gc2 * 8;

  f32x4 acc[4][4] = {};

  g2l16(gA1, &Alds[0][w * 512]); g2l16(gA2, &Alds[0][2048 + w * 512]);
  g2l16(gB1, &Blds[0][w * 512]); g2l16(gB2, &Blds[0][2048 + w * 512]);
  gA1 += 32; gA2 += 32; gB1 += 32; gB2 += 32;

  int cur = 0;
#pragma unroll 1
  for (int kt = 0; kt < 32; ++kt) {
    if (kt < 31) {
      g2l16(gA1, &Alds[cur ^ 1][w * 512]); g2l16(gA2, &Alds[cur ^ 1][2048 + w * 512]);
      g2l16(gB1, &Blds[cur ^ 1][w * 512]); g2l16(gB2, &Blds[cur ^ 1][2048 + w * 512]);
      gA1 += 32; gA2 += 32; gB1 += 32; gB2 += 32;
      asm volatile("s_waitcnt vmcnt(4)" ::: "memory");
    } else {
      asm volatile("s_waitcnt vmcnt(0)" ::: "memory");
    }
    __builtin_amdgcn_s_barrier();
    short8 af[4], bf[4];
#pragma unroll
    for (int mi = 0; mi < 4; ++mi) af[mi] = *(const short8*)&Alds[cur][aoff[mi]];
#pragma unroll
    for (int ni = 0; ni < 4; ++ni) bf[ni] = *(const short8*)&Blds[cur][boff[ni]];
#pragma unroll
    for (int mi = 0; mi < 4; ++mi)
#pragma unroll
      for (int ni = 0; ni < 4; ++ni)
        acc[mi][ni] = __builtin_amdgcn_mfma_f32_16x16x32_bf16(af[mi], bf[ni], acc[mi][ni], 0, 0, 0);
    __builtin_amdgcn_s_barrier();
    cur ^= 1;
  }

#pragma unroll
  for (int mi = 0; mi < 4; ++mi) {
    int mb = m0 + wm + mi * 16 + g * 4;
#pragma unroll
    for (int ni = 0; ni < 4; ++ni) {
      int n = n0 + wn + ni * 16 + li;
#pragma unroll
      for (int r = 0; r < 4; ++r)
        C[(size_t)(mb + r) * 1024 + n] = acc[mi][ni][r];
    }
  }
}

// ---------------------------------------------------------------- attention v8
// Swapped QK^T (s = mfma(K, Q)) with PERMUTED K-fragment rows so each lane's
// score output already holds exactly the keys its PV A-slots need (in-lane P,
// no LDS/bpermute). Softmax fully in-register. LDS = 32 KB.
__global__ __launch_bounds__(256, 4) void attn_kernel(const unsigned short* __restrict__ Qp,
                                                      const unsigned short* __restrict__ Kp,
                                                      const unsigned short* __restrict__ Vt,
                                                      const float* __restrict__ bias,
                                                      const unsigned* __restrict__ flagmask,
                                                      unsigned short* __restrict__ att) {
  __shared__ unsigned short Klds[2][64 * 64];   // 16 KB
  __shared__ unsigned short Vlds[2][64 * 64];   // 16 KB

  const int tid = threadIdx.x, lane = tid & 63, w = tid >> 6;
  const int g = lane >> 4, li = lane & 15;

  const int rid = blockIdx.x + (blockIdx.y << 4);
  const int xcd = rid & 7, kk = rid >> 3;
  const int bh = (kk & 7) | (xcd << 3);
  const int b = bh >> 4, h = bh & 15;
  const int tA = kk >> 3, tB = 31 - tA;
  const int nA = tA + 1, nB = tB + 1;

  const unsigned smask = flagmask[b];

  const int s1 = tid, s2 = tid + 256;
  const int r1 = s1 >> 3, c1 = (s1 & 7) ^ (r1 & 7);
  const int r2 = s2 >> 3, c2 = (s2 & 7) ^ (r2 & 7);
  const unsigned short* Kb1 = Kp + (size_t)(b * 2048 + r1) * 1024 + h * 64 + c1 * 8;
  const unsigned short* Kb2 = Kp + (size_t)(b * 2048 + r2) * 1024 + h * 64 + c2 * 8;
  const unsigned short* Vb1 = Vt + (size_t)(b * 1024 + h * 64 + r1) * 2048 + c1 * 8;
  const unsigned short* Vb2 = Vt + (size_t)(b * 1024 + h * 64 + r2) * 2048 + c2 * 8;

  int foffK[2][4], foffV[2][4];
#pragma unroll
  for (int ks = 0; ks < 2; ++ks)
#pragma unroll
    for (int ni = 0; ni < 4; ++ni) {
      const int krow = (ni >> 1) * 32 + (li >> 2) * 8 + (ni & 1) * 4 + (li & 3);
      foffK[ks][ni] = krow * 64 + (((ks * 4 + g) ^ (krow & 7)) * 8);
      const int vrow = ni * 16 + li;
      foffV[ks][ni] = vrow * 64 + (((ks * 4 + g) ^ (vrow & 7)) * 8);
    }

  const float* bbase = bias + b * 2048 + g * 8;

  short8 ones;
#pragma unroll
  for (int j2 = 0; j2 < 8; ++j2) ones[j2] = (short)0x3F80;  // bf16 1.0

  int qw = tA * 64 + w * 16;
  short8 qfr[2];
#pragma unroll
  for (int ks = 0; ks < 2; ++ks)
    qfr[ks] = *(const short8*)&Qp[((size_t)(b * 2048 + qw + li)) * 1024 +
                                  h * 64 + ks * 32 + g * 8];

  f32x4 acco[4] = {};
  f32x4 lacc = {};
  float m = -3.0e38f;                        // running max for q-row qw+li
  const f32x4 Z = {0.f, 0.f, 0.f, 0.f};

  auto stage = [&](int kt, int bufn) {
    const size_t ko = (size_t)kt * 65536, vo = (size_t)kt * 64;
    g2l16(Kb1 + ko, &Klds[bufn][w * 512]);
    g2l16(Kb2 + ko, &Klds[bufn][2048 + w * 512]);
    g2l16(Vb1 + vo, &Vlds[bufn][w * 512]);
    g2l16(Vb2 + vo, &Vlds[bufn][2048 + w * 512]);
  };

  auto body = [&](int kt, bool diag, int buf) {
    f32x4 s[4];
    __builtin_amdgcn_s_setprio(1);
#pragma unroll
    for (int ni = 0; ni < 4; ++ni) {
      short8 kf = *(const short8*)&Klds[buf][foffK[0][ni]];
      s[ni] = __builtin_amdgcn_mfma_f32_16x16x32_bf16(kf, qfr[0], Z, 0, 0, 0);
    }
#pragma unroll
    for (int ni = 0; ni < 4; ++ni) {
      short8 kf = *(const short8*)&Klds[buf][foffK[1][ni]];
      s[ni] = __builtin_amdgcn_mfma_f32_16x16x32_bf16(kf, qfr[1], s[ni], 0, 0, 0);
    }
    __builtin_amdgcn_s_setprio(0);
    if ((smask >> kt) & 1u) {
#pragma unroll
      for (int ni = 0; ni < 4; ++ni) {
        f32x4 bv = *(const f32x4*)&bbase[kt * 64 + (ni >> 1) * 32 + (ni & 1) * 4];
#pragma unroll
        for (int r = 0; r < 4; ++r) s[ni][r] += bv[r];
      }
    }
    if (diag) {
      const int q0 = qw + li;
#pragma unroll
      for (int ni = 0; ni < 4; ++ni) {
        const int kb = kt * 64 + (ni >> 1) * 32 + g * 8 + (ni & 1) * 4;
#pragma unroll
        for (int r = 0; r < 4; ++r)
          if (kb + r > q0) s[ni][r] = -1.0e9f;
      }
    }
    f32x4 tv;
#pragma unroll
    for (int r = 0; r < 4; ++r)
      tv[r] = fmaxf(fmaxf(s[0][r], s[1][r]), fmaxf(s[2][r], s[3][r]));
    float tm = fmaxf(fmaxf(tv[0], tv[1]), fmaxf(tv[2], tv[3]));
    tm = fmaxf(tm, __shfl_xor(tm, 16));
    tm = fmaxf(tm, __shfl_xor(tm, 32));
    if (__any(tm > m + 8.0f)) {
      const float mn = fmaxf(m, tm);
      const float al = __builtin_amdgcn_exp2f(m - mn);
      m = mn;
      float alpv[4];
#pragma unroll
      for (int r = 0; r < 4; ++r)
        alpv[r] = __builtin_bit_cast(float,
            __builtin_amdgcn_ds_bpermute((g * 4 + r) * 4, __builtin_bit_cast(int, al)));
#pragma unroll
      for (int r = 0; r < 4; ++r) {
        lacc[r] *= alpv[r];
#pragma unroll
        for (int df = 0; df < 4; ++df) acco[df][r] *= alpv[r];
      }
    }
    unsigned wpk[4][2];
#pragma unroll
    for (int ni = 0; ni < 4; ++ni) {
#pragma unroll
      for (int a2 = 0; a2 < 2; ++a2) {
        float lo = __builtin_amdgcn_exp2f(s[ni][2 * a2]     - m);
        float hi = __builtin_amdgcn_exp2f(s[ni][2 * a2 + 1] - m);
        wpk[ni][a2] = cvt_pk_bf16(lo, hi);
      }
    }
#pragma unroll
    for (int ks = 0; ks < 2; ++ks) {
      u32x4 pw = { wpk[2 * ks][0], wpk[2 * ks][1], wpk[2 * ks + 1][0], wpk[2 * ks + 1][1] };
      const short8 pa = __builtin_bit_cast(short8, pw);
      short8 vf[4];
#pragma unroll
      for (int df = 0; df < 4; ++df) vf[df] = *(const short8*)&Vlds[buf][foffV[ks][df]];
      __builtin_amdgcn_s_setprio(1);
#pragma unroll
      for (int df = 0; df < 4; ++df)
        acco[df] = __builtin_amdgcn_mfma_f32_16x16x32_bf16(pa, vf[df], acco[df], 0, 0, 0);
      lacc = __builtin_amdgcn_mfma_f32_16x16x32_bf16(pa, ones, lacc, 0, 0, 0);
      __builtin_amdgcn_s_setprio(0);
    }
  };

  auto epilogue = [&]() {
    float inv[4];
#pragma unroll
    for (int r = 0; r < 4; ++r) inv[r] = __builtin_amdgcn_rcpf(lacc[r]);
    const int qb0 = qw + g * 4;
#pragma unroll
    for (int df = 0; df < 4; ++df) {
      const int d = h * 64 + df * 16 + li;
#pragma unroll
      for (int r = 0; r < 4; ++r)
        att[(size_t)(b * 2048 + qb0 + r) * 1024 + d] = f2bf(acco[df][r] * inv[r]);
    }
  };

  stage(0, 0);
  int buf = 0;

#pragma unroll 1
  for (int kt = 0; kt < nA; ++kt) {
    stage((kt + 1 < nA) ? kt + 1 : 0, buf ^ 1);
    asm volatile("s_waitcnt vmcnt(4)" ::: "memory");
    __builtin_amdgcn_s_barrier();
    body(kt, kt == nA - 1, buf);
    __builtin_amdgcn_s_barrier();
    buf ^= 1;
  }

  epilogue();
  qw = tB * 64 + w * 16;
#pragma unroll
  for (int ks = 0; ks < 2; ++ks)
    qfr[ks] = *(const short8*)&Qp[((size_t)(b * 2048 + qw + li)) * 1024 +
                                  h * 64 + ks * 32 + g * 8];
#pragma unroll
  for (int df = 0; df < 4; ++df) acco[df] = Z;
  lacc = Z;
  m = -3.0e38f;

#pragma unroll 1
  for (int kt = 0; kt < nB; ++kt) {
    if (kt + 1 < nB) {
      stage(kt + 1, buf ^ 1);
      asm volatile("s_waitcnt vmcnt(4)" ::: "memory");
    } else {
      asm volatile("s_waitcnt vmcnt(0)" ::: "memory");
    }
    __builtin_amdgcn_s_barrier();
    body(kt, kt == nB - 1, buf);
    __builtin_amdgcn_s_barrier();
    buf ^= 1;
  }

  epilogue();
}

// ---------------------------------------------------------------- launch
extern "C" void kernel_launch(void* const* d_in, const int* in_sizes, int n_in,
                              void* d_out, int out_size, void* d_ws, size_t ws_size,
                              hipStream_t stream) {
  const float* q_raw  = (const float*)d_in[0];
  const float* kv_raw = (const float*)d_in[1];
  const int*   pmask  = (const int*)d_in[2];
  const float* Wq = (const float*)d_in[3];
  const float* Wk = (const float*)d_in[4];
  const float* Wv = (const float*)d_in[5];
  const float* Wo = (const float*)d_in[6];
  float* out = (float*)d_out;

  const size_t NEL = 8388608;   // B*S*D
  const size_t WEL = 1048576;   // D*D
  unsigned short* ws   = (unsigned short*)d_ws;
  unsigned short* qbf  = ws;              // reused as att after projections
  unsigned short* kvbf = qbf + NEL;
  unsigned short* wbf  = kvbf + NEL;      // Wq,Wk,Wv,Wo bf16 back-to-back
  unsigned short* Qp   = wbf + 4 * WEL;
  unsigned short* Kp   = Qp + NEL;
  unsigned short* Vtp  = Kp + NEL;        // (B,H,DH,S) transposed V
  float*          bias = (float*)(Vtp + NEL);
  unsigned*       flagmask = (unsigned*)(bias + 8192);
  unsigned short* att  = qbf;             // alias (qbf dead after projections)

  const float sc = 0.125f * 1.44269504088896340736f;  // 1/sqrt(DH) * log2(e)

  cvt6<<<dim3(512, 6), 256, 0, stream>>>(q_raw, kv_raw, Wq, Wk, Wv, Wo, qbf, kvbf, wbf);
  bias_kernel<<<4, 1024, 0, stream>>>(pmask, bias, flagmask);
  gemm_proj<<<768, 512, 0, stream>>>(qbf, kvbf, wbf, Qp, Kp, Vtp, sc);
  attn_kernel<<<dim3(16, 64), 256, 0, stream>>>(Qp, Kp, Vtp, bias, flagmask, att);
  gemm_out<<<512, 256, 0, stream>>>(att, wbf + 3 * WEL, out);
}